// Round 13
// baseline (1194.070 us; speedup 1.0000x reference)
//
#include <hip/hip_runtime.h>
#include <math.h>

#define EPSC   1e-6f
#define BNEPS  1e-5f
#define NSWEEP_A    5     // passA (r12 post-mortem: revert to r11 known-good)
#define NSWEEP_B    5     // passB: direct output accuracy (6->0.0078, 5->0.0166, thr 0.0248)
#define NSWEEP_STAT 8

// static workspace layout (float offsets)
#define OFF_BM      0
#define OFF_BMSQ    4096
#define OFF_BMISQ   8192
#define OFF_MEANSQ  12288
#define OFF_RMISQ   16384
#define OFF_SVEC    20480
#define OFF_PART1   32768           // 256*4096 (k_mean1 only; overlaps gtblk in time)
#define OFF_DYN     32768           // dynamic: gtblk[NE*1024] | sllblk[NE*32] | gt2[64*1024] | sll2[64]

typedef float v2f __attribute__((ext_vector_type(2)));

__device__ __forceinline__ v2f mkv(float x, float y) { v2f r; r.x = x; r.y = y; return r; }
__device__ __forceinline__ int swz(int f, int j) { return f ^ ((j & 7) << 2); }
__device__ __forceinline__ float4 pk4(const v2f a, const v2f b) {
    return make_float4(a.x, a.y, b.x, b.y);
}

__device__ __forceinline__ float dotp(const v2f x[16], const v2f y[16]) {
    v2f a0 = x[0] * y[0];
    v2f a1 = x[1] * y[1];
    v2f a2 = x[2] * y[2];
    v2f a3 = x[3] * y[3];
#pragma unroll
    for (int i = 4; i < 16; i += 4) {
        a0 = __builtin_elementwise_fma(x[i+0], y[i+0], a0);
        a1 = __builtin_elementwise_fma(x[i+1], y[i+1], a1);
        a2 = __builtin_elementwise_fma(x[i+2], y[i+2], a2);
        a3 = __builtin_elementwise_fma(x[i+3], y[i+3], a3);
    }
    v2f s = (a0 + a1) + (a2 + a3);
    return s.x + s.y;
}

// One packed Jacobi micro-rotation on column pair (x owned, y copy/owned).
// isp: x is the globally-smaller column. Pair lanes compute identical params.
template<bool UPDY>
__device__ __forceinline__ void microrot_p(v2f x[16], float& ax, v2f y[16], float& ay, bool isp) {
    float gg = dotp(x, y);
    float aa = isp ? ax : ay;
    float bb = isp ? ay : ax;
    bool tiny = (fabsf(gg) < 1e-30f);
    float tau = (bb - aa) * 0.5f * __builtin_amdgcn_rcpf(gg);
    float t = copysignf(__builtin_amdgcn_rcpf(
                  fabsf(tau) + __builtin_amdgcn_sqrtf(fmaf(tau, tau, 1.f))), tau);
    t = tiny ? 0.f : t;
    float cc = __builtin_amdgcn_rsqf(fmaf(t, t, 1.f));
    float s = t * cc;
    float se = isp ? -s : s;
    float te = isp ? -t : t;
    v2f c2 = mkv(cc, cc), s2 = mkv(se, se), ns2 = mkv(-se, -se);
#pragma unroll
    for (int i = 0; i < 16; ++i) {
        v2f xo = x[i];
        x[i] = __builtin_elementwise_fma(s2, y[i], c2 * x[i]);
        if (UPDY) y[i] = __builtin_elementwise_fma(ns2, xo, c2 * y[i]);
    }
    ax = fmaf(te, gg, ax);
    if (UPDY) ay = fmaf(-te, gg, ay);
}

// Blocked-2 one-sided Jacobi, packed. Lane r of a 16-lane group owns cols
// 2r, 2r+1. Per sweep: in-lane pair + 15 XOR-mask exchanges, 4 micro-rots per
// exchange. 66 DS/step for 4 matrices/wave (r9 DS fix) + packed VALU (r8 fix).
template<int SWEEPS>
__device__ __forceinline__ void jacobi_b2p(v2f a0[16], v2f a1[16], float& al0, float& al1, int r) {
    al0 = dotp(a0, a0);
    al1 = dotp(a1, a1);
#pragma unroll 1
    for (int sweep = 0; sweep < SWEEPS; ++sweep) {
        microrot_p<true>(a0, al0, a1, al1, true);       // in-lane pair (2r,2r+1)
#pragma unroll 1
        for (int m = 1; m < 16; ++m) {
            v2f q0[16], q1[16];
#pragma unroll
            for (int i = 0; i < 16; ++i) {
                q0[i].x = __shfl_xor(a0[i].x, m);
                q0[i].y = __shfl_xor(a0[i].y, m);
                q1[i].x = __shfl_xor(a1[i].x, m);
                q1[i].y = __shfl_xor(a1[i].y, m);
            }
            float be0 = __shfl_xor(al0, m);
            float be1 = __shfl_xor(al1, m);
            __builtin_amdgcn_sched_barrier(0);
            bool isp = (r < (r ^ m));
            microrot_p<true >(a0, al0, q0, be0, isp);   // {2r,   2(r^m)}
            microrot_p<true >(a1, al1, q1, be1, isp);   // {2r+1, 2(r^m)+1}
            microrot_p<false>(a0, al0, q1, be1, isp);   // {2r,   2(r^m)+1}
            microrot_p<false>(a1, al1, q0, be0, isp);   // {2r+1, 2(r^m)}
        }
    }
}

// y{0,1} = M(swizzled LDS) . w{0,1}  (weights in registers)
__device__ __forceinline__ void mv2(const float* M, const float* w0a, const float* w1a,
                                    v2f y0[16], v2f y1[16]) {
#pragma unroll
    for (int j = 0; j < 32; ++j) {
        v2f w0 = mkv(w0a[j], w0a[j]);
        v2f w1 = mkv(w1a[j], w1a[j]);
#pragma unroll
        for (int t = 0; t < 8; ++t) {
            float4 v = *(const float4*)(M + swz(j * 32 + 4 * t, j));
            v2f lo = mkv(v.x, v.y), hi = mkv(v.z, v.w);
            if (j == 0) {
                y0[2*t] = w0 * lo; y0[2*t+1] = w0 * hi;
                y1[2*t] = w1 * lo; y1[2*t+1] = w1 * hi;
            } else {
                y0[2*t]   = __builtin_elementwise_fma(w0, lo, y0[2*t]);
                y0[2*t+1] = __builtin_elementwise_fma(w0, hi, y0[2*t+1]);
                y1[2*t]   = __builtin_elementwise_fma(w1, lo, y1[2*t]);
                y1[2*t+1] = __builtin_elementwise_fma(w1, hi, y1[2*t+1]);
            }
        }
    }
}

// y{0,1}[i] = sum_j (cf_j*) M[j][c{0,1}] * Mcol_j[i]  (A A^T-style recon)
template<bool USE_CF>
__device__ __forceinline__ void mv2w(const float* M, const float* cf, int c0, int c1,
                                     v2f y0[16], v2f y1[16]) {
#pragma unroll
    for (int j = 0; j < 32; ++j) {
        float w0s = M[swz(j * 32 + c0, j)];
        float w1s = M[swz(j * 32 + c1, j)];
        if (USE_CF) { w0s *= cf[j]; w1s *= cf[j]; }
        v2f w0 = mkv(w0s, w0s);
        v2f w1 = mkv(w1s, w1s);
#pragma unroll
        for (int t = 0; t < 8; ++t) {
            float4 v = *(const float4*)(M + swz(j * 32 + 4 * t, j));
            v2f lo = mkv(v.x, v.y), hi = mkv(v.z, v.w);
            if (j == 0) {
                y0[2*t] = w0 * lo; y0[2*t+1] = w0 * hi;
                y1[2*t] = w1 * lo; y1[2*t+1] = w1 * hi;
            } else {
                y0[2*t]   = __builtin_elementwise_fma(w0, lo, y0[2*t]);
                y0[2*t+1] = __builtin_elementwise_fma(w0, hi, y0[2*t+1]);
                y1[2*t]   = __builtin_elementwise_fma(w1, lo, y1[2*t]);
                y1[2*t+1] = __builtin_elementwise_fma(w1, hi, y1[2*t+1]);
            }
        }
    }
}

// ---------- legacy scalar helpers (prep/stats/fallback) ----------

template<int SWEEPS>
__device__ __forceinline__ void jacobi32(float a[32], int k) {
    float alpha = 0.f;
#pragma unroll
    for (int i = 0; i < 32; ++i) alpha = fmaf(a[i], a[i], alpha);
#pragma unroll 1
    for (int sweep = 0; sweep < SWEEPS; ++sweep) {
#pragma unroll 1
        for (int m = 1; m < 32; ++m) {
            float q[32];
#pragma unroll
            for (int i = 0; i < 32; ++i) q[i] = __shfl_xor(a[i], m);
            float beta = __shfl_xor(alpha, m);
            float g0=0.f,g1=0.f,g2=0.f,g3=0.f,g4=0.f,g5=0.f,g6=0.f,g7=0.f;
#pragma unroll
            for (int i = 0; i < 32; i += 8) {
                g0 = fmaf(a[i+0], q[i+0], g0);
                g1 = fmaf(a[i+1], q[i+1], g1);
                g2 = fmaf(a[i+2], q[i+2], g2);
                g3 = fmaf(a[i+3], q[i+3], g3);
                g4 = fmaf(a[i+4], q[i+4], g4);
                g5 = fmaf(a[i+5], q[i+5], g5);
                g6 = fmaf(a[i+6], q[i+6], g6);
                g7 = fmaf(a[i+7], q[i+7], g7);
            }
            float gam = ((g0+g1)+(g2+g3))+((g4+g5)+(g6+g7));
            bool isp = (k < (k ^ m));
            float aa = isp ? alpha : beta;
            float bb = isp ? beta  : alpha;
            bool tiny = (fabsf(gam) < 1e-30f);
            float tau = (bb - aa) * 0.5f * __builtin_amdgcn_rcpf(gam);
            float t = copysignf(__builtin_amdgcn_rcpf(
                          fabsf(tau) + __builtin_amdgcn_sqrtf(fmaf(tau, tau, 1.f))), tau);
            t = tiny ? 0.f : t;
            float c = __builtin_amdgcn_rsqf(fmaf(t, t, 1.f));
            float s = t * c;
            float se = isp ? -s : s;
            float te = isp ? -t : t;
#pragma unroll
            for (int i = 0; i < 32; ++i) a[i] = fmaf(se, q[i], c * a[i]);
            alpha = fmaf(te, gam, alpha);
        }
    }
}

__device__ __forceinline__ void matvec32(const float* M, const float v[32], float y[32]) {
    {
        const float4* col = (const float4*)M;
        float vj = v[0];
#pragma unroll
        for (int t = 0; t < 8; ++t) {
            float4 r = col[t];
            y[4*t+0] = vj*r.x; y[4*t+1] = vj*r.y; y[4*t+2] = vj*r.z; y[4*t+3] = vj*r.w;
        }
    }
#pragma unroll
    for (int j = 1; j < 32; ++j) {
        const float4* col = (const float4*)(M + j * 32);
        float vj = v[j];
#pragma unroll
        for (int t = 0; t < 8; ++t) {
            float4 r = col[t];
            y[4*t+0] = fmaf(vj, r.x, y[4*t+0]);
            y[4*t+1] = fmaf(vj, r.y, y[4*t+1]);
            y[4*t+2] = fmaf(vj, r.z, y[4*t+2]);
            y[4*t+3] = fmaf(vj, r.w, y[4*t+3]);
        }
    }
}

__device__ __forceinline__ void read_vec(const float* M, int k, float v[32]) {
    const float4* src = (const float4*)(M + k * 32);
#pragma unroll
    for (int t = 0; t < 8; ++t) {
        float4 r = src[t];
        v[4*t+0] = r.x; v[4*t+1] = r.y; v[4*t+2] = r.z; v[4*t+3] = r.w;
    }
}

__device__ __forceinline__ void stage_vec(float* M, int k, const float v[32]) {
    float4* dst = (float4*)(M + k * 32);
#pragma unroll
    for (int t = 0; t < 8; ++t)
        dst[t] = make_float4(v[4*t+0], v[4*t+1], v[4*t+2], v[4*t+3]);
}

template<bool ACC, bool USE_COEF>
__device__ __forceinline__ void recon32(const float* Acols, const float* coef, int k, float out[32]) {
    if (!ACC) {
        float w = Acols[k];
        if (USE_COEF) w *= coef[0];
        const float4* col = (const float4*)Acols;
#pragma unroll
        for (int t = 0; t < 8; ++t) {
            float4 r = col[t];
            out[4*t+0] = w*r.x; out[4*t+1] = w*r.y; out[4*t+2] = w*r.z; out[4*t+3] = w*r.w;
        }
    }
    for (int j = (ACC ? 0 : 1); j < 32; ++j) {
        float w = Acols[j * 32 + k];
        if (USE_COEF) w *= coef[j];
        const float4* col = (const float4*)(Acols + j * 32);
#pragma unroll
        for (int t = 0; t < 8; ++t) {
            float4 r = col[t];
            out[4*t+0] = fmaf(w, r.x, out[4*t+0]);
            out[4*t+1] = fmaf(w, r.y, out[4*t+1]);
            out[4*t+2] = fmaf(w, r.z, out[4*t+2]);
            out[4*t+3] = fmaf(w, r.w, out[4*t+3]);
        }
    }
}

// ---------- kernels ----------

__global__ __launch_bounds__(256) void k_mean1(const float* __restrict__ X, float* __restrict__ part) {
    int bi = blockIdx.x;
    int tid = threadIdx.x;
    const float* xb = X + (size_t)bi * 16 * 4096;
#pragma unroll
    for (int q = 0; q < 16; ++q) {
        int e = q * 256 + tid;
        float acc = 0.f;
        for (int b = 0; b < 16; ++b) acc += xb[(size_t)b * 4096 + e];
        part[(size_t)bi * 4096 + e] = acc;
    }
}

// 64 blocks x 64 elements; serial depth 64.
__global__ __launch_bounds__(256) void k_mean2(const float* __restrict__ part, float* __restrict__ bm) {
    __shared__ float red[4][64];
    int bi = blockIdx.x, tid = threadIdx.x;
    int eh = tid & 63, q = tid >> 6;
    int e = bi * 64 + eh;
    float acc = 0.f;
    for (int p = q * 64; p < q * 64 + 64; ++p) acc += part[(size_t)p * 4096 + e];
    red[q][eh] = acc;
    __syncthreads();
    if (q == 0)
        bm[e] = (red[0][eh] + red[1][eh] + red[2][eh] + red[3][eh]) * (1.f / 4096.f);
}

// eig(bm[c]) -> bm_sq, bm_isq ; eig(mean[c]) -> mean_sq.  1 block, 8 half-waves.
__global__ __launch_bounds__(256) void k_prep(const float* __restrict__ wsbm, const float* __restrict__ meang,
                                              float* __restrict__ bmsq, float* __restrict__ bmisq,
                                              float* __restrict__ msq) {
    __shared__ __align__(16) float mat[8][1024];
    __shared__ __align__(16) float aslot[8][1024];
    __shared__ float coefA[8][32];
    __shared__ float coefB[4][32];
    int tid = threadIdx.x;
    for (int i = tid; i < 4096; i += 256) {
        ((float*)mat)[i] = wsbm[i];
        ((float*)mat)[4096 + i] = meang[i];
    }
    __syncthreads();
    int hwl = tid >> 5, k = tid & 31;
    float a[32];
    read_vec(mat[hwl], k, a);
    jacobi32<NSWEEP_STAT>(a, k);
    float al = 0.f;
#pragma unroll
    for (int i = 0; i < 32; ++i) al = fmaf(a[i], a[i], al);
    al = fmaxf(al, 1e-30f);
    float lam = sqrtf(al);
    float inv_al = 1.f / al;
    if (hwl < 4) {
        float wc = fmaxf(lam, EPSC);
        float sqw = sqrtf(wc);
        coefA[hwl][k] = sqw * inv_al;
        coefB[hwl][k] = (1.f / sqw) * inv_al;
    } else {
        float wc = fmaxf(lam, 0.f);
        coefA[hwl][k] = sqrtf(wc) * inv_al;
    }
    stage_vec(aslot[hwl], k, a);
    __syncthreads();
    float o[32];
    recon32<false, true>(aslot[hwl], coefA[hwl], k, o);
    if (hwl < 4) {
        float* dst = bmsq + hwl * 1024 + k * 32;
#pragma unroll
        for (int i = 0; i < 32; ++i) dst[i] = o[i];
        recon32<false, true>(aslot[hwl], coefB[hwl], k, o);
        float* dst2 = bmisq + hwl * 1024 + k * 32;
#pragma unroll
        for (int i = 0; i < 32; ++i) dst2[i] = o[i];
    } else {
        float* dst = msq + (hwl - 4) * 1024 + k * 32;
#pragma unroll
        for (int i = 0; i < 32; ++i) dst[i] = o[i];
    }
}

// pass A blocked-2 packed: 256 threads = 16 groups of 16 lanes, one matrix per
// group, 2 cols per lane. Grid 1024 (16384 matrices). Channel = bi & 3.
// Cross-group reduce is a fully barriered binary tree (r12 post-mortem: the
// lockstep-visibility assumption is replaced by __syncthreads()).
__global__ __launch_bounds__(256) void k_passA_b2(const float* __restrict__ X, const float* __restrict__ bmisq_g,
                                                  float* __restrict__ gtblk, float* __restrict__ sllblk) {
    __shared__ __align__(16) float slot[16][1028];   // 16B stagger between groups
    __shared__ __align__(16) float bmi[1024];
    __shared__ float coefs[16][33];
    __shared__ float sl[16][16];
    const int tid = threadIdx.x;
    const int g = tid >> 4, r = tid & 15;
    const int c0 = 2 * r, c1 = 2 * r + 1;
    const int bi = blockIdx.x;
    const int ch = bi & 3;
    const int gidx = (((bi >> 2) * 16) + g) * 4 + ch;

    {   // stage bmi swizzled (256 float4 / 256 threads)
        const float4* src = (const float4*)(bmisq_g + ch * 1024);
        int i4 = tid;
        *(float4*)(bmi + swz(4 * i4, i4 >> 3)) = src[i4];
    }
    {   // stage X swizzled (coalesced within group)
        const float4* xg = (const float4*)(X + (size_t)gidx * 1024);
        float* sg = slot[g];
#pragma unroll
        for (int q = 0; q < 16; ++q) {
            int i4 = q * 16 + r;
            *(float4*)(sg + swz(4 * i4, i4 >> 3)) = xg[i4];
        }
    }
    // B cols c0,c1 from global (L2-hot, avoids LDS column conflicts)
    float b0f[32], b1f[32];
    {
        const float4* bs = (const float4*)(bmisq_g + ch * 1024);
#pragma unroll
        for (int t = 0; t < 8; ++t) {
            float4 v0 = bs[c0 * 8 + t];
            b0f[4*t+0]=v0.x; b0f[4*t+1]=v0.y; b0f[4*t+2]=v0.z; b0f[4*t+3]=v0.w;
            float4 v1 = bs[c1 * 8 + t];
            b1f[4*t+0]=v1.x; b1f[4*t+1]=v1.y; b1f[4*t+2]=v1.z; b1f[4*t+3]=v1.w;
        }
    }
    __syncthreads();
    // y = X * b  (2 cols)
    v2f y0[16], y1[16];
    mv2(slot[g], b0f, b1f, y0, y1);
    // a = B * y  (uniform broadcast over block-shared bmi)
    v2f a0[16], a1[16];
    {
        float w0a[32], w1a[32];
#pragma unroll
        for (int u = 0; u < 16; ++u) {
            w0a[2*u] = y0[u].x; w0a[2*u+1] = y0[u].y;
            w1a[2*u] = y1[u].x; w1a[2*u+1] = y1[u].y;
        }
        mv2(bmi, w0a, w1a, a0, a1);
    }
    float al0, al1;
    jacobi_b2p<NSWEEP_A>(a0, a1, al0, al1, r);
    al0 = fmaxf(al0, 1e-30f); al1 = fmaxf(al1, 1e-30f);
    float l0 = logf(fmaxf(sqrtf(al0), EPSC));
    float l1 = logf(fmaxf(sqrtf(al1), EPSC));
    sl[g][r] = l0 * l0 + l1 * l1;
    coefs[g][c0] = l0 / al0;
    coefs[g][c1] = l1 / al1;
    {   // stage eigvec-scaled cols (overwrite X; group-private, same-wave order)
        float* sg = slot[g];
#pragma unroll
        for (int t = 0; t < 8; ++t) {
            *(float4*)(sg + swz(c0 * 32 + 4 * t, c0)) = pk4(a0[2*t], a0[2*t+1]);
            *(float4*)(sg + swz(c1 * 32 + 4 * t, c1)) = pk4(a1[2*t], a1[2*t+1]);
        }
    }
    // recon logm cols c0,c1
    v2f o0[16], o1[16];
    mv2w<true>(slot[g], coefs[g], c0, c1, o0, o1);
    {   // stage logm partials for cross-group reduce
        float* sg = slot[g];
#pragma unroll
        for (int t = 0; t < 8; ++t) {
            *(float4*)(sg + swz(c0 * 32 + 4 * t, c0)) = pk4(o0[2*t], o0[2*t+1]);
            *(float4*)(sg + swz(c1 * 32 + 4 * t, c1)) = pk4(o1[2*t], o1[2*t+1]);
        }
    }
    // barriered binary-tree reduce over the 16 group slots
#pragma unroll
    for (int stride = 8; stride >= 1; stride >>= 1) {
        __syncthreads();
        if (g < stride) {
            const float* sh = slot[g + stride];
#pragma unroll
            for (int t = 0; t < 8; ++t) {
                float4 v0 = *(const float4*)(sh + swz(c0 * 32 + 4 * t, c0));
                o0[2*t] += mkv(v0.x, v0.y); o0[2*t+1] += mkv(v0.z, v0.w);
                float4 v1 = *(const float4*)(sh + swz(c1 * 32 + 4 * t, c1));
                o1[2*t] += mkv(v1.x, v1.y); o1[2*t+1] += mkv(v1.z, v1.w);
            }
            if (stride > 1) {
                float* sg = slot[g];
#pragma unroll
                for (int t = 0; t < 8; ++t) {
                    *(float4*)(sg + swz(c0 * 32 + 4 * t, c0)) = pk4(o0[2*t], o0[2*t+1]);
                    *(float4*)(sg + swz(c1 * 32 + 4 * t, c1)) = pk4(o1[2*t], o1[2*t+1]);
                }
            }
        }
    }
    if (g == 0) {
        float* dst = gtblk + (size_t)bi * 1024;
#pragma unroll
        for (int t = 0; t < 8; ++t) {
            *(float4*)(dst + c0 * 32 + 4 * t) = pk4(o0[2*t], o0[2*t+1]);
            *(float4*)(dst + c1 * 32 + 4 * t) = pk4(o1[2*t], o1[2*t+1]);
        }
        float st = 0.f;
#pragma unroll
        for (int h = 0; h < 16; ++h) st += sl[h][r];
        sllblk[(size_t)bi * 32 + r] = st;
        sllblk[(size_t)bi * 32 + 16 + r] = 0.f;
    }
}

// pass A looped fallback (small workspace), scalar legacy structure.
__global__ __launch_bounds__(256) void k_passAL(const float* __restrict__ X, const float* __restrict__ bmisq_g,
                                                float* __restrict__ gtblk, float* __restrict__ sllblk,
                                                int rounds, int bstride) {
    __shared__ __align__(16) float slot[8][1024];
    __shared__ __align__(16) float bmi[1024];
    __shared__ float coef[8][32];
    __shared__ float sllred[8][32];
    int tid = threadIdx.x;
    int hwl = tid >> 5, k = tid & 31;
    int bi = blockIdx.x;
    int c = bi & 3;
    int b0 = (bi >> 2) * 8 + hwl;
    for (int i = tid; i < 1024; i += 256) bmi[i] = bmisq_g[c * 1024 + i];
    float gt[32];
#pragma unroll
    for (int i = 0; i < 32; ++i) gt[i] = 0.f;
    float sll = 0.f;
    __syncthreads();
#pragma unroll 1
    for (int rr = 0; rr < rounds; ++rr) {
        int g = (b0 + rr * bstride) * 4 + c;
        const float4* xg = (const float4*)(X + (size_t)g * 1024);
        float4* xs = (float4*)slot[hwl];
#pragma unroll
        for (int i = 0; i < 8; ++i) xs[i * 32 + k] = xg[i * 32 + k];
        float a[32];
        {
            float mk[32]; read_vec(bmi, k, mk);
            float y[32];  matvec32(slot[hwl], mk, y);
            matvec32(bmi, y, a);
        }
        jacobi32<NSWEEP_B>(a, k);
        float al = 0.f;
#pragma unroll
        for (int i = 0; i < 32; ++i) al = fmaf(a[i], a[i], al);
        al = fmaxf(al, 1e-30f);
        float l = logf(fmaxf(sqrtf(al), EPSC));
        sll = fmaf(l, l, sll);
        stage_vec(slot[hwl], k, a);
        coef[hwl][k] = l / al;
        recon32<true, true>(slot[hwl], coef[hwl], k, gt);
    }
    sllred[hwl][k] = sll;
    if (hwl >= 4) stage_vec(slot[hwl], k, gt);
    __syncthreads();
    if (hwl < 4) {
        const float* p = slot[hwl + 4] + k * 32;
#pragma unroll
        for (int i = 0; i < 32; ++i) gt[i] += p[i];
    }
    if (hwl == 2 || hwl == 3) stage_vec(slot[hwl], k, gt);
    __syncthreads();
    if (hwl < 2) {
        const float* p = slot[hwl + 2] + k * 32;
#pragma unroll
        for (int i = 0; i < 32; ++i) gt[i] += p[i];
    }
    if (hwl == 1) stage_vec(slot[1], k, gt);
    __syncthreads();
    if (hwl == 0) {
        const float* p = slot[1] + k * 32;
        float* dst = gtblk + (size_t)bi * 1024 + k * 32;
#pragma unroll
        for (int i = 0; i < 32; ++i) dst[i] = gt[i] + p[i];
        float stot = 0.f;
#pragma unroll
        for (int h = 0; h < 8; ++h) stot += sllred[h][k];
        sllblk[(size_t)bi * 32 + k] = stot;
    }
}

// reduce NE block-partials -> 16 segment partials per channel (T = NE/64),
// and reduce sllblk -> one scalar per (seg, channel).
__global__ __launch_bounds__(256) void k_red(const float* __restrict__ gtblk, const float* __restrict__ sllblk,
                                             float* __restrict__ gt2, float* __restrict__ sll2, int T) {
    int bi = blockIdx.x;                // 64
    int c = bi & 3, seg = bi >> 2;
    int tid = threadIdx.x;
#pragma unroll
    for (int q = 0; q < 4; ++q) {
        int e = q * 256 + tid;
        float acc = 0.f;
        for (int t = 0; t < T; ++t) {
            int blk = (seg * T + t) * 4 + c;
            acc += gtblk[(size_t)blk * 1024 + e];
        }
        gt2[((size_t)seg * 4 + c) * 1024 + e] = acc;
    }
    __shared__ float sred[256];
    float sacc = 0.f;
    for (int idx = tid; idx < T * 32; idx += 256) {
        int t = idx >> 5, r = idx & 31;
        int blk = (seg * T + t) * 4 + c;
        sacc += sllblk[(size_t)blk * 32 + r];
    }
    sred[tid] = sacc;
    __syncthreads();
    for (int off = 128; off > 0; off >>= 1) {
        if (tid < off) sred[tid] += sred[tid + off];
        __syncthreads();
    }
    if (tid == 0) sll2[seg * 4 + c] = sred[0];
}

// finish GT, batch_var, s; eig(GT) -> expm -> rm; eig(rm) -> rm_isq.
__global__ __launch_bounds__(256) void k_stats(const float* __restrict__ gt2, const float* __restrict__ sll2,
                                               const float* __restrict__ stdg, const float* __restrict__ bmsq_g,
                                               float* __restrict__ rmisq_g, float* __restrict__ svec_g) {
    __shared__ __align__(16) float GTl[4][1024];
    __shared__ __align__(16) float bmsq[4][1024];
    __shared__ __align__(16) float slot[8][1024];
    __shared__ float coef[4][32];
    int tid = threadIdx.x;
    for (int i = tid; i < 4096; i += 256) {
        int cc = i >> 10, e = i & 1023;
        float acc = 0.f;
        for (int seg = 0; seg < 16; ++seg) acc += gt2[((size_t)seg * 4 + cc) * 1024 + e];
        ((float*)GTl)[i] = acc * (1.f / 4096.f);
        ((float*)bmsq)[i] = bmsq_g[i];
    }
    __syncthreads();
    if (tid < 4) {
        float tot = 0.f;
        for (int seg = 0; seg < 16; ++seg) tot += sll2[seg * 4 + tid];
        float sll_mean = tot * (1.f / 4096.f);
        float ssq = 0.f;
        for (int e = 0; e < 1024; ++e) { float v = GTl[tid][e]; ssq = fmaf(v, v, ssq); }
        float bvar = fmaxf(sll_mean - ssq, 0.f);     // batch_var = E||XT||^2 - ||GT||^2
        float s = stdg[tid] / sqrtf(bvar + BNEPS);
        svec_g[tid] = s;
    }
    __syncthreads();
    int hwl = tid >> 5, k = tid & 31;
    if (hwl < 4) {
        int c = hwl;
        float a[32]; read_vec(GTl[c], k, a);
        jacobi32<NSWEEP_STAT>(a, k);
        float s2 = 0.f;
#pragma unroll
        for (int i = 0; i < 32; ++i) s2 = fmaf(a[i], a[i], s2);
        s2 = fmaxf(s2, 1e-30f);
        float y[32]; matvec32(GTl[c], a, y);
        float num = 0.f;
#pragma unroll
        for (int i = 0; i < 32; ++i) num = fmaf(a[i], y[i], num);
        float rho = num / s2;                       // signed eigenvalue (Rayleigh)
        coef[hwl][k] = expf(rho) / s2;
        stage_vec(slot[hwl], k, a);
    }
    __syncthreads();
    if (hwl < 4) {
        float ex[32];
        recon32<false, true>(slot[hwl], coef[hwl], k, ex);
        stage_vec(slot[hwl + 4], k, ex);
    }
    __syncthreads();
    if (hwl < 4) {
        int c = hwl;
        float v1[32]; read_vec(bmsq[c], k, v1);
        float v2[32]; matvec32(slot[hwl + 4], v1, v2);
        float rmc[32]; matvec32(bmsq[c], v2, rmc);
        stage_vec(slot[hwl], k, rmc);
    }
    __syncthreads();
    if (hwl < 4) {
        float a[32]; read_vec(slot[hwl], k, a);
        jacobi32<NSWEEP_STAT>(a, k);
        float al = 0.f;
#pragma unroll
        for (int i = 0; i < 32; ++i) al = fmaf(a[i], a[i], al);
        al = fmaxf(al, 1e-30f);
        float wc = fmaxf(sqrtf(al), EPSC);
        coef[hwl][k] = (1.f / sqrtf(wc)) / al;
        stage_vec(slot[hwl], k, a);
    }
    __syncthreads();
    if (hwl < 4) {
        float o[32];
        recon32<false, true>(slot[hwl], coef[hwl], k, o);
        float* dst = rmisq_g + hwl * 1024 + k * 32;
#pragma unroll
        for (int i = 0; i < 32; ++i) dst[i] = o[i];
    }
}

// pass B blocked-2 packed: group-private slots throughout (no cross-group LDS).
__global__ __launch_bounds__(256) void k_passB_b2(const float* __restrict__ X, const float* __restrict__ rmisq_g,
                                                  const float* __restrict__ msq_g, const float* __restrict__ svec_g,
                                                  float* __restrict__ out) {
    __shared__ __align__(16) float slot[16][1028];
    __shared__ __align__(16) float rmi[1024];
    __shared__ __align__(16) float msl[1024];
    const int tid = threadIdx.x;
    const int g = tid >> 4, r = tid & 15;
    const int c0 = 2 * r, c1 = 2 * r + 1;
    const int bi = blockIdx.x;
    const int ch = bi & 3;
    const int gidx = (((bi >> 2) * 16) + g) * 4 + ch;
    const float sv = svec_g[ch];

    {   // stage rmi + msl swizzled
        const float4* s1 = (const float4*)(rmisq_g + ch * 1024);
        const float4* s2 = (const float4*)(msq_g + ch * 1024);
        int i4 = tid;
        *(float4*)(rmi + swz(4 * i4, i4 >> 3)) = s1[i4];
        *(float4*)(msl + swz(4 * i4, i4 >> 3)) = s2[i4];
    }
    {   // stage X swizzled
        const float4* xg = (const float4*)(X + (size_t)gidx * 1024);
        float* sg = slot[g];
#pragma unroll
        for (int q = 0; q < 16; ++q) {
            int i4 = q * 16 + r;
            *(float4*)(sg + swz(4 * i4, i4 >> 3)) = xg[i4];
        }
    }
    float b0f[32], b1f[32];
    {
        const float4* bs = (const float4*)(rmisq_g + ch * 1024);
#pragma unroll
        for (int t = 0; t < 8; ++t) {
            float4 v0 = bs[c0 * 8 + t];
            b0f[4*t+0]=v0.x; b0f[4*t+1]=v0.y; b0f[4*t+2]=v0.z; b0f[4*t+3]=v0.w;
            float4 v1 = bs[c1 * 8 + t];
            b1f[4*t+0]=v1.x; b1f[4*t+1]=v1.y; b1f[4*t+2]=v1.z; b1f[4*t+3]=v1.w;
        }
    }
    __syncthreads();
    v2f y0[16], y1[16];
    mv2(slot[g], b0f, b1f, y0, y1);                    // X * rmi-cols
    v2f a0[16], a1[16];
    {
        float w0a[32], w1a[32];
#pragma unroll
        for (int u = 0; u < 16; ++u) {
            w0a[2*u] = y0[u].x; w0a[2*u+1] = y0[u].y;
            w1a[2*u] = y1[u].x; w1a[2*u+1] = y1[u].y;
        }
        mv2(rmi, w0a, w1a, a0, a1);                    // inner cols c0,c1
    }
    float al0, al1;
    jacobi_b2p<NSWEEP_B>(a0, a1, al0, al1, r);
    al0 = fmaxf(al0, 1e-30f); al1 = fmaxf(al1, 1e-30f);
    float wc0 = fmaxf(sqrtf(al0), EPSC);
    float wc1 = fmaxf(sqrtf(al1), EPSC);
    float scl0 = sqrtf(expf(sv * logf(wc0)) / al0);    // sqrt(lam^s)/lam
    float scl1 = sqrtf(expf(sv * logf(wc1)) / al1);
    v2f cc0[16], cc1[16];
    {
        float w0a[32], w1a[32];
#pragma unroll
        for (int u = 0; u < 16; ++u) {
            w0a[2*u] = a0[u].x * scl0; w0a[2*u+1] = a0[u].y * scl0;
            w1a[2*u] = a1[u].x * scl1; w1a[2*u+1] = a1[u].y * scl1;
        }
        mv2(msl, w0a, w1a, cc0, cc1);                  // C cols = mean_sq * bh
    }
    {   // stage C (overwrite X; group-private, same-wave order)
        float* sg = slot[g];
#pragma unroll
        for (int t = 0; t < 8; ++t) {
            *(float4*)(sg + swz(c0 * 32 + 4 * t, c0)) = pk4(cc0[2*t], cc0[2*t+1]);
            *(float4*)(sg + swz(c1 * 32 + 4 * t, c1)) = pk4(cc1[2*t], cc1[2*t+1]);
        }
    }
    v2f x0[16], x1[16];
    mv2w<false>(slot[g], (const float*)nullptr, c0, c1, x0, x1);   // Xn = C C^T
    float* dst = out + (size_t)gidx * 1024;
#pragma unroll
    for (int u = 0; u < 16; ++u) {
        *(float2*)(dst + (2*u) * 32 + c0)     = make_float2(x0[u].x, x1[u].x);
        *(float2*)(dst + (2*u + 1) * 32 + c0) = make_float2(x0[u].y, x1[u].y);
    }
}

extern "C" void kernel_launch(void* const* d_in, const int* in_sizes, int n_in,
                              void* d_out, int out_size, void* d_ws, size_t ws_size,
                              hipStream_t stream) {
    const float* X     = (const float*)d_in[0];
    // d_in[1] running_mean, d_in[2] running_var: drop out exactly for ETA=1
    const float* meang = (const float*)d_in[3];
    const float* stdg  = (const float*)d_in[4];
    float* out = (float*)d_out;
    float* ws  = (float*)d_ws;
    (void)in_sizes; (void)n_in; (void)out_size;

    auto need = [](size_t ne) -> size_t {
        return (size_t)(32768ull + ne * 1024ull + ne * 32ull + 65536ull + 64ull) * 4ull;
    };
    int NE = (ws_size >= need(1024)) ? 1024 : 512;
    float* gtblk  = ws + OFF_DYN;
    float* sllblk = gtblk + (size_t)NE * 1024;
    float* gt2    = sllblk + (size_t)NE * 32;
    float* sll2   = gt2 + 65536;

    k_mean1<<<256, 256, 0, stream>>>(X, ws + OFF_PART1);
    k_mean2<<<64, 256, 0, stream>>>(ws + OFF_PART1, ws + OFF_BM);
    k_prep <<<1, 256, 0, stream>>>(ws + OFF_BM, meang, ws + OFF_BMSQ, ws + OFF_BMISQ, ws + OFF_MEANSQ);
    if (NE == 1024) {
        k_passA_b2<<<1024, 256, 0, stream>>>(X, ws + OFF_BMISQ, gtblk, sllblk);
    } else {
        k_passAL<<<512, 256, 0, stream>>>(X, ws + OFF_BMISQ, gtblk, sllblk, 4, 1024);
    }
    k_red  <<<64, 256, 0, stream>>>(gtblk, sllblk, gt2, sll2, NE / 64);
    k_stats<<<1, 256, 0, stream>>>(gt2, sll2, stdg, ws + OFF_BMSQ, ws + OFF_RMISQ, ws + OFF_SVEC);
    k_passB_b2<<<1024, 256, 0, stream>>>(X, ws + OFF_RMISQ, ws + OFF_MEANSQ, ws + OFF_SVEC, out);
}

// Round 14
// 1137.470 us; speedup vs baseline: 1.0498x; 1.0498x over previous
//
#include <hip/hip_runtime.h>
#include <math.h>

#define EPSC   1e-6f
#define BNEPS  1e-5f
#define NSWEEP_A    4     // passA: err averages into channel stats over 4096 samples.
                          // r12 first-validation with A=4 passed at 0.0195 (its replay
                          // failure was the lockstep-reduce race, fixed in r13).
#define NSWEEP_B    5     // passB: direct output accuracy (6->0.0078, 5->0.0166-0.0195, thr 0.0248)
#define NSWEEP_STAT 8

// static workspace layout (float offsets)
#define OFF_BM      0
#define OFF_BMSQ    4096
#define OFF_BMISQ   8192
#define OFF_MEANSQ  12288
#define OFF_RMISQ   16384
#define OFF_SVEC    20480
#define OFF_PART1   32768           // 256*4096 (k_mean1 only; overlaps gtblk in time)
#define OFF_DYN     32768           // dynamic: gtblk[NE*1024] | sllblk[NE*32] | gt2[64*1024] | sll2[64]

typedef float v2f __attribute__((ext_vector_type(2)));

__device__ __forceinline__ v2f mkv(float x, float y) { v2f r; r.x = x; r.y = y; return r; }
__device__ __forceinline__ int swz(int f, int j) { return f ^ ((j & 7) << 2); }
__device__ __forceinline__ float4 pk4(const v2f a, const v2f b) {
    return make_float4(a.x, a.y, b.x, b.y);
}

__device__ __forceinline__ float dotp(const v2f x[16], const v2f y[16]) {
    v2f a0 = x[0] * y[0];
    v2f a1 = x[1] * y[1];
    v2f a2 = x[2] * y[2];
    v2f a3 = x[3] * y[3];
#pragma unroll
    for (int i = 4; i < 16; i += 4) {
        a0 = __builtin_elementwise_fma(x[i+0], y[i+0], a0);
        a1 = __builtin_elementwise_fma(x[i+1], y[i+1], a1);
        a2 = __builtin_elementwise_fma(x[i+2], y[i+2], a2);
        a3 = __builtin_elementwise_fma(x[i+3], y[i+3], a3);
    }
    v2f s = (a0 + a1) + (a2 + a3);
    return s.x + s.y;
}

// One packed Jacobi micro-rotation on column pair (x owned, y copy/owned).
// isp: x is the globally-smaller column. Pair lanes compute identical params.
template<bool UPDY>
__device__ __forceinline__ void microrot_p(v2f x[16], float& ax, v2f y[16], float& ay, bool isp) {
    float gg = dotp(x, y);
    float aa = isp ? ax : ay;
    float bb = isp ? ay : ax;
    bool tiny = (fabsf(gg) < 1e-30f);
    float tau = (bb - aa) * 0.5f * __builtin_amdgcn_rcpf(gg);
    float t = copysignf(__builtin_amdgcn_rcpf(
                  fabsf(tau) + __builtin_amdgcn_sqrtf(fmaf(tau, tau, 1.f))), tau);
    t = tiny ? 0.f : t;
    float cc = __builtin_amdgcn_rsqf(fmaf(t, t, 1.f));
    float s = t * cc;
    float se = isp ? -s : s;
    float te = isp ? -t : t;
    v2f c2 = mkv(cc, cc), s2 = mkv(se, se), ns2 = mkv(-se, -se);
#pragma unroll
    for (int i = 0; i < 16; ++i) {
        v2f xo = x[i];
        x[i] = __builtin_elementwise_fma(s2, y[i], c2 * x[i]);
        if (UPDY) y[i] = __builtin_elementwise_fma(ns2, xo, c2 * y[i]);
    }
    ax = fmaf(te, gg, ax);
    if (UPDY) ay = fmaf(-te, gg, ay);
}

// Blocked-2 one-sided Jacobi, packed. Lane r of a 16-lane group owns cols
// 2r, 2r+1. Per sweep: in-lane pair + 15 XOR-mask exchanges, 4 micro-rots per
// exchange. 66 DS/step for 4 matrices/wave (r9 DS fix) + packed VALU (r8 fix).
template<int SWEEPS>
__device__ __forceinline__ void jacobi_b2p(v2f a0[16], v2f a1[16], float& al0, float& al1, int r) {
    al0 = dotp(a0, a0);
    al1 = dotp(a1, a1);
#pragma unroll 1
    for (int sweep = 0; sweep < SWEEPS; ++sweep) {
        microrot_p<true>(a0, al0, a1, al1, true);       // in-lane pair (2r,2r+1)
#pragma unroll 1
        for (int m = 1; m < 16; ++m) {
            v2f q0[16], q1[16];
#pragma unroll
            for (int i = 0; i < 16; ++i) {
                q0[i].x = __shfl_xor(a0[i].x, m);
                q0[i].y = __shfl_xor(a0[i].y, m);
                q1[i].x = __shfl_xor(a1[i].x, m);
                q1[i].y = __shfl_xor(a1[i].y, m);
            }
            float be0 = __shfl_xor(al0, m);
            float be1 = __shfl_xor(al1, m);
            __builtin_amdgcn_sched_barrier(0);
            bool isp = (r < (r ^ m));
            microrot_p<true >(a0, al0, q0, be0, isp);   // {2r,   2(r^m)}
            microrot_p<true >(a1, al1, q1, be1, isp);   // {2r+1, 2(r^m)+1}
            microrot_p<false>(a0, al0, q1, be1, isp);   // {2r,   2(r^m)+1}
            microrot_p<false>(a1, al1, q0, be0, isp);   // {2r+1, 2(r^m)}
        }
    }
}

// y{0,1} = M(swizzled LDS) . w{0,1}  (weights in registers)
__device__ __forceinline__ void mv2(const float* M, const float* w0a, const float* w1a,
                                    v2f y0[16], v2f y1[16]) {
#pragma unroll
    for (int j = 0; j < 32; ++j) {
        v2f w0 = mkv(w0a[j], w0a[j]);
        v2f w1 = mkv(w1a[j], w1a[j]);
#pragma unroll
        for (int t = 0; t < 8; ++t) {
            float4 v = *(const float4*)(M + swz(j * 32 + 4 * t, j));
            v2f lo = mkv(v.x, v.y), hi = mkv(v.z, v.w);
            if (j == 0) {
                y0[2*t] = w0 * lo; y0[2*t+1] = w0 * hi;
                y1[2*t] = w1 * lo; y1[2*t+1] = w1 * hi;
            } else {
                y0[2*t]   = __builtin_elementwise_fma(w0, lo, y0[2*t]);
                y0[2*t+1] = __builtin_elementwise_fma(w0, hi, y0[2*t+1]);
                y1[2*t]   = __builtin_elementwise_fma(w1, lo, y1[2*t]);
                y1[2*t+1] = __builtin_elementwise_fma(w1, hi, y1[2*t+1]);
            }
        }
    }
}

// y{0,1}[i] = sum_j (cf_j*) M[j][c{0,1}] * Mcol_j[i]  (A A^T-style recon)
template<bool USE_CF>
__device__ __forceinline__ void mv2w(const float* M, const float* cf, int c0, int c1,
                                     v2f y0[16], v2f y1[16]) {
#pragma unroll
    for (int j = 0; j < 32; ++j) {
        float w0s = M[swz(j * 32 + c0, j)];
        float w1s = M[swz(j * 32 + c1, j)];
        if (USE_CF) { w0s *= cf[j]; w1s *= cf[j]; }
        v2f w0 = mkv(w0s, w0s);
        v2f w1 = mkv(w1s, w1s);
#pragma unroll
        for (int t = 0; t < 8; ++t) {
            float4 v = *(const float4*)(M + swz(j * 32 + 4 * t, j));
            v2f lo = mkv(v.x, v.y), hi = mkv(v.z, v.w);
            if (j == 0) {
                y0[2*t] = w0 * lo; y0[2*t+1] = w0 * hi;
                y1[2*t] = w1 * lo; y1[2*t+1] = w1 * hi;
            } else {
                y0[2*t]   = __builtin_elementwise_fma(w0, lo, y0[2*t]);
                y0[2*t+1] = __builtin_elementwise_fma(w0, hi, y0[2*t+1]);
                y1[2*t]   = __builtin_elementwise_fma(w1, lo, y1[2*t]);
                y1[2*t+1] = __builtin_elementwise_fma(w1, hi, y1[2*t+1]);
            }
        }
    }
}

// ---------- legacy scalar helpers (prep/stats/fallback) ----------

template<int SWEEPS>
__device__ __forceinline__ void jacobi32(float a[32], int k) {
    float alpha = 0.f;
#pragma unroll
    for (int i = 0; i < 32; ++i) alpha = fmaf(a[i], a[i], alpha);
#pragma unroll 1
    for (int sweep = 0; sweep < SWEEPS; ++sweep) {
#pragma unroll 1
        for (int m = 1; m < 32; ++m) {
            float q[32];
#pragma unroll
            for (int i = 0; i < 32; ++i) q[i] = __shfl_xor(a[i], m);
            float beta = __shfl_xor(alpha, m);
            float g0=0.f,g1=0.f,g2=0.f,g3=0.f,g4=0.f,g5=0.f,g6=0.f,g7=0.f;
#pragma unroll
            for (int i = 0; i < 32; i += 8) {
                g0 = fmaf(a[i+0], q[i+0], g0);
                g1 = fmaf(a[i+1], q[i+1], g1);
                g2 = fmaf(a[i+2], q[i+2], g2);
                g3 = fmaf(a[i+3], q[i+3], g3);
                g4 = fmaf(a[i+4], q[i+4], g4);
                g5 = fmaf(a[i+5], q[i+5], g5);
                g6 = fmaf(a[i+6], q[i+6], g6);
                g7 = fmaf(a[i+7], q[i+7], g7);
            }
            float gam = ((g0+g1)+(g2+g3))+((g4+g5)+(g6+g7));
            bool isp = (k < (k ^ m));
            float aa = isp ? alpha : beta;
            float bb = isp ? beta  : alpha;
            bool tiny = (fabsf(gam) < 1e-30f);
            float tau = (bb - aa) * 0.5f * __builtin_amdgcn_rcpf(gam);
            float t = copysignf(__builtin_amdgcn_rcpf(
                          fabsf(tau) + __builtin_amdgcn_sqrtf(fmaf(tau, tau, 1.f))), tau);
            t = tiny ? 0.f : t;
            float c = __builtin_amdgcn_rsqf(fmaf(t, t, 1.f));
            float s = t * c;
            float se = isp ? -s : s;
            float te = isp ? -t : t;
#pragma unroll
            for (int i = 0; i < 32; ++i) a[i] = fmaf(se, q[i], c * a[i]);
            alpha = fmaf(te, gam, alpha);
        }
    }
}

__device__ __forceinline__ void matvec32(const float* M, const float v[32], float y[32]) {
    {
        const float4* col = (const float4*)M;
        float vj = v[0];
#pragma unroll
        for (int t = 0; t < 8; ++t) {
            float4 r = col[t];
            y[4*t+0] = vj*r.x; y[4*t+1] = vj*r.y; y[4*t+2] = vj*r.z; y[4*t+3] = vj*r.w;
        }
    }
#pragma unroll
    for (int j = 1; j < 32; ++j) {
        const float4* col = (const float4*)(M + j * 32);
        float vj = v[j];
#pragma unroll
        for (int t = 0; t < 8; ++t) {
            float4 r = col[t];
            y[4*t+0] = fmaf(vj, r.x, y[4*t+0]);
            y[4*t+1] = fmaf(vj, r.y, y[4*t+1]);
            y[4*t+2] = fmaf(vj, r.z, y[4*t+2]);
            y[4*t+3] = fmaf(vj, r.w, y[4*t+3]);
        }
    }
}

__device__ __forceinline__ void read_vec(const float* M, int k, float v[32]) {
    const float4* src = (const float4*)(M + k * 32);
#pragma unroll
    for (int t = 0; t < 8; ++t) {
        float4 r = src[t];
        v[4*t+0] = r.x; v[4*t+1] = r.y; v[4*t+2] = r.z; v[4*t+3] = r.w;
    }
}

__device__ __forceinline__ void stage_vec(float* M, int k, const float v[32]) {
    float4* dst = (float4*)(M + k * 32);
#pragma unroll
    for (int t = 0; t < 8; ++t)
        dst[t] = make_float4(v[4*t+0], v[4*t+1], v[4*t+2], v[4*t+3]);
}

template<bool ACC, bool USE_COEF>
__device__ __forceinline__ void recon32(const float* Acols, const float* coef, int k, float out[32]) {
    if (!ACC) {
        float w = Acols[k];
        if (USE_COEF) w *= coef[0];
        const float4* col = (const float4*)Acols;
#pragma unroll
        for (int t = 0; t < 8; ++t) {
            float4 r = col[t];
            out[4*t+0] = w*r.x; out[4*t+1] = w*r.y; out[4*t+2] = w*r.z; out[4*t+3] = w*r.w;
        }
    }
    for (int j = (ACC ? 0 : 1); j < 32; ++j) {
        float w = Acols[j * 32 + k];
        if (USE_COEF) w *= coef[j];
        const float4* col = (const float4*)(Acols + j * 32);
#pragma unroll
        for (int t = 0; t < 8; ++t) {
            float4 r = col[t];
            out[4*t+0] = fmaf(w, r.x, out[4*t+0]);
            out[4*t+1] = fmaf(w, r.y, out[4*t+1]);
            out[4*t+2] = fmaf(w, r.z, out[4*t+2]);
            out[4*t+3] = fmaf(w, r.w, out[4*t+3]);
        }
    }
}

// ---------- kernels ----------

__global__ __launch_bounds__(256) void k_mean1(const float* __restrict__ X, float* __restrict__ part) {
    int bi = blockIdx.x;
    int tid = threadIdx.x;
    const float* xb = X + (size_t)bi * 16 * 4096;
#pragma unroll
    for (int q = 0; q < 16; ++q) {
        int e = q * 256 + tid;
        float acc = 0.f;
        for (int b = 0; b < 16; ++b) acc += xb[(size_t)b * 4096 + e];
        part[(size_t)bi * 4096 + e] = acc;
    }
}

// 64 blocks x 64 elements; serial depth 64.
__global__ __launch_bounds__(256) void k_mean2(const float* __restrict__ part, float* __restrict__ bm) {
    __shared__ float red[4][64];
    int bi = blockIdx.x, tid = threadIdx.x;
    int eh = tid & 63, q = tid >> 6;
    int e = bi * 64 + eh;
    float acc = 0.f;
    for (int p = q * 64; p < q * 64 + 64; ++p) acc += part[(size_t)p * 4096 + e];
    red[q][eh] = acc;
    __syncthreads();
    if (q == 0)
        bm[e] = (red[0][eh] + red[1][eh] + red[2][eh] + red[3][eh]) * (1.f / 4096.f);
}

// eig(bm[c]) -> bm_sq, bm_isq ; eig(mean[c]) -> mean_sq.  1 block, 8 half-waves.
__global__ __launch_bounds__(256) void k_prep(const float* __restrict__ wsbm, const float* __restrict__ meang,
                                              float* __restrict__ bmsq, float* __restrict__ bmisq,
                                              float* __restrict__ msq) {
    __shared__ __align__(16) float mat[8][1024];
    __shared__ __align__(16) float aslot[8][1024];
    __shared__ float coefA[8][32];
    __shared__ float coefB[4][32];
    int tid = threadIdx.x;
    for (int i = tid; i < 4096; i += 256) {
        ((float*)mat)[i] = wsbm[i];
        ((float*)mat)[4096 + i] = meang[i];
    }
    __syncthreads();
    int hwl = tid >> 5, k = tid & 31;
    float a[32];
    read_vec(mat[hwl], k, a);
    jacobi32<NSWEEP_STAT>(a, k);
    float al = 0.f;
#pragma unroll
    for (int i = 0; i < 32; ++i) al = fmaf(a[i], a[i], al);
    al = fmaxf(al, 1e-30f);
    float lam = sqrtf(al);
    float inv_al = 1.f / al;
    if (hwl < 4) {
        float wc = fmaxf(lam, EPSC);
        float sqw = sqrtf(wc);
        coefA[hwl][k] = sqw * inv_al;
        coefB[hwl][k] = (1.f / sqw) * inv_al;
    } else {
        float wc = fmaxf(lam, 0.f);
        coefA[hwl][k] = sqrtf(wc) * inv_al;
    }
    stage_vec(aslot[hwl], k, a);
    __syncthreads();
    float o[32];
    recon32<false, true>(aslot[hwl], coefA[hwl], k, o);
    if (hwl < 4) {
        float* dst = bmsq + hwl * 1024 + k * 32;
#pragma unroll
        for (int i = 0; i < 32; ++i) dst[i] = o[i];
        recon32<false, true>(aslot[hwl], coefB[hwl], k, o);
        float* dst2 = bmisq + hwl * 1024 + k * 32;
#pragma unroll
        for (int i = 0; i < 32; ++i) dst2[i] = o[i];
    } else {
        float* dst = msq + (hwl - 4) * 1024 + k * 32;
#pragma unroll
        for (int i = 0; i < 32; ++i) dst[i] = o[i];
    }
}

// pass A blocked-2 packed: 256 threads = 16 groups of 16 lanes, one matrix per
// group, 2 cols per lane. Grid 1024 (16384 matrices). Channel = bi & 3.
// Cross-group reduce: fully barriered binary tree (r12/r13: replay-race fix).
__global__ __launch_bounds__(256) void k_passA_b2(const float* __restrict__ X, const float* __restrict__ bmisq_g,
                                                  float* __restrict__ gtblk, float* __restrict__ sllblk) {
    __shared__ __align__(16) float slot[16][1028];   // 16B stagger between groups
    __shared__ __align__(16) float bmi[1024];
    __shared__ float coefs[16][33];
    __shared__ float sl[16][16];
    const int tid = threadIdx.x;
    const int g = tid >> 4, r = tid & 15;
    const int c0 = 2 * r, c1 = 2 * r + 1;
    const int bi = blockIdx.x;
    const int ch = bi & 3;
    const int gidx = (((bi >> 2) * 16) + g) * 4 + ch;

    {   // stage bmi swizzled (256 float4 / 256 threads)
        const float4* src = (const float4*)(bmisq_g + ch * 1024);
        int i4 = tid;
        *(float4*)(bmi + swz(4 * i4, i4 >> 3)) = src[i4];
    }
    {   // stage X swizzled (coalesced within group)
        const float4* xg = (const float4*)(X + (size_t)gidx * 1024);
        float* sg = slot[g];
#pragma unroll
        for (int q = 0; q < 16; ++q) {
            int i4 = q * 16 + r;
            *(float4*)(sg + swz(4 * i4, i4 >> 3)) = xg[i4];
        }
    }
    // B cols c0,c1 from global (L2-hot, avoids LDS column conflicts)
    float b0f[32], b1f[32];
    {
        const float4* bs = (const float4*)(bmisq_g + ch * 1024);
#pragma unroll
        for (int t = 0; t < 8; ++t) {
            float4 v0 = bs[c0 * 8 + t];
            b0f[4*t+0]=v0.x; b0f[4*t+1]=v0.y; b0f[4*t+2]=v0.z; b0f[4*t+3]=v0.w;
            float4 v1 = bs[c1 * 8 + t];
            b1f[4*t+0]=v1.x; b1f[4*t+1]=v1.y; b1f[4*t+2]=v1.z; b1f[4*t+3]=v1.w;
        }
    }
    __syncthreads();
    // y = X * b  (2 cols)
    v2f y0[16], y1[16];
    mv2(slot[g], b0f, b1f, y0, y1);
    // a = B * y  (uniform broadcast over block-shared bmi)
    v2f a0[16], a1[16];
    {
        float w0a[32], w1a[32];
#pragma unroll
        for (int u = 0; u < 16; ++u) {
            w0a[2*u] = y0[u].x; w0a[2*u+1] = y0[u].y;
            w1a[2*u] = y1[u].x; w1a[2*u+1] = y1[u].y;
        }
        mv2(bmi, w0a, w1a, a0, a1);
    }
    float al0, al1;
    jacobi_b2p<NSWEEP_A>(a0, a1, al0, al1, r);
    al0 = fmaxf(al0, 1e-30f); al1 = fmaxf(al1, 1e-30f);
    float l0 = logf(fmaxf(sqrtf(al0), EPSC));
    float l1 = logf(fmaxf(sqrtf(al1), EPSC));
    sl[g][r] = l0 * l0 + l1 * l1;
    coefs[g][c0] = l0 / al0;
    coefs[g][c1] = l1 / al1;
    {   // stage eigvec-scaled cols (overwrite X; group-private, same-wave order)
        float* sg = slot[g];
#pragma unroll
        for (int t = 0; t < 8; ++t) {
            *(float4*)(sg + swz(c0 * 32 + 4 * t, c0)) = pk4(a0[2*t], a0[2*t+1]);
            *(float4*)(sg + swz(c1 * 32 + 4 * t, c1)) = pk4(a1[2*t], a1[2*t+1]);
        }
    }
    // recon logm cols c0,c1
    v2f o0[16], o1[16];
    mv2w<true>(slot[g], coefs[g], c0, c1, o0, o1);
    {   // stage logm partials for cross-group reduce
        float* sg = slot[g];
#pragma unroll
        for (int t = 0; t < 8; ++t) {
            *(float4*)(sg + swz(c0 * 32 + 4 * t, c0)) = pk4(o0[2*t], o0[2*t+1]);
            *(float4*)(sg + swz(c1 * 32 + 4 * t, c1)) = pk4(o1[2*t], o1[2*t+1]);
        }
    }
    // barriered binary-tree reduce over the 16 group slots
#pragma unroll
    for (int stride = 8; stride >= 1; stride >>= 1) {
        __syncthreads();
        if (g < stride) {
            const float* sh = slot[g + stride];
#pragma unroll
            for (int t = 0; t < 8; ++t) {
                float4 v0 = *(const float4*)(sh + swz(c0 * 32 + 4 * t, c0));
                o0[2*t] += mkv(v0.x, v0.y); o0[2*t+1] += mkv(v0.z, v0.w);
                float4 v1 = *(const float4*)(sh + swz(c1 * 32 + 4 * t, c1));
                o1[2*t] += mkv(v1.x, v1.y); o1[2*t+1] += mkv(v1.z, v1.w);
            }
            if (stride > 1) {
                float* sg = slot[g];
#pragma unroll
                for (int t = 0; t < 8; ++t) {
                    *(float4*)(sg + swz(c0 * 32 + 4 * t, c0)) = pk4(o0[2*t], o0[2*t+1]);
                    *(float4*)(sg + swz(c1 * 32 + 4 * t, c1)) = pk4(o1[2*t], o1[2*t+1]);
                }
            }
        }
    }
    if (g == 0) {
        float* dst = gtblk + (size_t)bi * 1024;
#pragma unroll
        for (int t = 0; t < 8; ++t) {
            *(float4*)(dst + c0 * 32 + 4 * t) = pk4(o0[2*t], o0[2*t+1]);
            *(float4*)(dst + c1 * 32 + 4 * t) = pk4(o1[2*t], o1[2*t+1]);
        }
        float st = 0.f;
#pragma unroll
        for (int h = 0; h < 16; ++h) st += sl[h][r];
        sllblk[(size_t)bi * 32 + r] = st;
        sllblk[(size_t)bi * 32 + 16 + r] = 0.f;
    }
}

// pass A looped fallback (small workspace), scalar legacy structure.
__global__ __launch_bounds__(256) void k_passAL(const float* __restrict__ X, const float* __restrict__ bmisq_g,
                                                float* __restrict__ gtblk, float* __restrict__ sllblk,
                                                int rounds, int bstride) {
    __shared__ __align__(16) float slot[8][1024];
    __shared__ __align__(16) float bmi[1024];
    __shared__ float coef[8][32];
    __shared__ float sllred[8][32];
    int tid = threadIdx.x;
    int hwl = tid >> 5, k = tid & 31;
    int bi = blockIdx.x;
    int c = bi & 3;
    int b0 = (bi >> 2) * 8 + hwl;
    for (int i = tid; i < 1024; i += 256) bmi[i] = bmisq_g[c * 1024 + i];
    float gt[32];
#pragma unroll
    for (int i = 0; i < 32; ++i) gt[i] = 0.f;
    float sll = 0.f;
    __syncthreads();
#pragma unroll 1
    for (int rr = 0; rr < rounds; ++rr) {
        int g = (b0 + rr * bstride) * 4 + c;
        const float4* xg = (const float4*)(X + (size_t)g * 1024);
        float4* xs = (float4*)slot[hwl];
#pragma unroll
        for (int i = 0; i < 8; ++i) xs[i * 32 + k] = xg[i * 32 + k];
        float a[32];
        {
            float mk[32]; read_vec(bmi, k, mk);
            float y[32];  matvec32(slot[hwl], mk, y);
            matvec32(bmi, y, a);
        }
        jacobi32<NSWEEP_B>(a, k);
        float al = 0.f;
#pragma unroll
        for (int i = 0; i < 32; ++i) al = fmaf(a[i], a[i], al);
        al = fmaxf(al, 1e-30f);
        float l = logf(fmaxf(sqrtf(al), EPSC));
        sll = fmaf(l, l, sll);
        stage_vec(slot[hwl], k, a);
        coef[hwl][k] = l / al;
        recon32<true, true>(slot[hwl], coef[hwl], k, gt);
    }
    sllred[hwl][k] = sll;
    if (hwl >= 4) stage_vec(slot[hwl], k, gt);
    __syncthreads();
    if (hwl < 4) {
        const float* p = slot[hwl + 4] + k * 32;
#pragma unroll
        for (int i = 0; i < 32; ++i) gt[i] += p[i];
    }
    if (hwl == 2 || hwl == 3) stage_vec(slot[hwl], k, gt);
    __syncthreads();
    if (hwl < 2) {
        const float* p = slot[hwl + 2] + k * 32;
#pragma unroll
        for (int i = 0; i < 32; ++i) gt[i] += p[i];
    }
    if (hwl == 1) stage_vec(slot[1], k, gt);
    __syncthreads();
    if (hwl == 0) {
        const float* p = slot[1] + k * 32;
        float* dst = gtblk + (size_t)bi * 1024 + k * 32;
#pragma unroll
        for (int i = 0; i < 32; ++i) dst[i] = gt[i] + p[i];
        float stot = 0.f;
#pragma unroll
        for (int h = 0; h < 8; ++h) stot += sllred[h][k];
        sllblk[(size_t)bi * 32 + k] = stot;
    }
}

// reduce NE block-partials -> 16 segment partials per channel (T = NE/64),
// and reduce sllblk -> one scalar per (seg, channel).
__global__ __launch_bounds__(256) void k_red(const float* __restrict__ gtblk, const float* __restrict__ sllblk,
                                             float* __restrict__ gt2, float* __restrict__ sll2, int T) {
    int bi = blockIdx.x;                // 64
    int c = bi & 3, seg = bi >> 2;
    int tid = threadIdx.x;
#pragma unroll
    for (int q = 0; q < 4; ++q) {
        int e = q * 256 + tid;
        float acc = 0.f;
        for (int t = 0; t < T; ++t) {
            int blk = (seg * T + t) * 4 + c;
            acc += gtblk[(size_t)blk * 1024 + e];
        }
        gt2[((size_t)seg * 4 + c) * 1024 + e] = acc;
    }
    __shared__ float sred[256];
    float sacc = 0.f;
    for (int idx = tid; idx < T * 32; idx += 256) {
        int t = idx >> 5, r = idx & 31;
        int blk = (seg * T + t) * 4 + c;
        sacc += sllblk[(size_t)blk * 32 + r];
    }
    sred[tid] = sacc;
    __syncthreads();
    for (int off = 128; off > 0; off >>= 1) {
        if (tid < off) sred[tid] += sred[tid + off];
        __syncthreads();
    }
    if (tid == 0) sll2[seg * 4 + c] = sred[0];
}

// finish GT, batch_var, s; eig(GT) -> expm -> rm; eig(rm) -> rm_isq.
__global__ __launch_bounds__(256) void k_stats(const float* __restrict__ gt2, const float* __restrict__ sll2,
                                               const float* __restrict__ stdg, const float* __restrict__ bmsq_g,
                                               float* __restrict__ rmisq_g, float* __restrict__ svec_g) {
    __shared__ __align__(16) float GTl[4][1024];
    __shared__ __align__(16) float bmsq[4][1024];
    __shared__ __align__(16) float slot[8][1024];
    __shared__ float coef[4][32];
    int tid = threadIdx.x;
    for (int i = tid; i < 4096; i += 256) {
        int cc = i >> 10, e = i & 1023;
        float acc = 0.f;
        for (int seg = 0; seg < 16; ++seg) acc += gt2[((size_t)seg * 4 + cc) * 1024 + e];
        ((float*)GTl)[i] = acc * (1.f / 4096.f);
        ((float*)bmsq)[i] = bmsq_g[i];
    }
    __syncthreads();
    if (tid < 4) {
        float tot = 0.f;
        for (int seg = 0; seg < 16; ++seg) tot += sll2[seg * 4 + tid];
        float sll_mean = tot * (1.f / 4096.f);
        float ssq = 0.f;
        for (int e = 0; e < 1024; ++e) { float v = GTl[tid][e]; ssq = fmaf(v, v, ssq); }
        float bvar = fmaxf(sll_mean - ssq, 0.f);     // batch_var = E||XT||^2 - ||GT||^2
        float s = stdg[tid] / sqrtf(bvar + BNEPS);
        svec_g[tid] = s;
    }
    __syncthreads();
    int hwl = tid >> 5, k = tid & 31;
    if (hwl < 4) {
        int c = hwl;
        float a[32]; read_vec(GTl[c], k, a);
        jacobi32<NSWEEP_STAT>(a, k);
        float s2 = 0.f;
#pragma unroll
    for (int i = 0; i < 32; ++i) s2 = fmaf(a[i], a[i], s2);
        s2 = fmaxf(s2, 1e-30f);
        float y[32]; matvec32(GTl[c], a, y);
        float num = 0.f;
#pragma unroll
        for (int i = 0; i < 32; ++i) num = fmaf(a[i], y[i], num);
        float rho = num / s2;                       // signed eigenvalue (Rayleigh)
        coef[hwl][k] = expf(rho) / s2;
        stage_vec(slot[hwl], k, a);
    }
    __syncthreads();
    if (hwl < 4) {
        float ex[32];
        recon32<false, true>(slot[hwl], coef[hwl], k, ex);
        stage_vec(slot[hwl + 4], k, ex);
    }
    __syncthreads();
    if (hwl < 4) {
        int c = hwl;
        float v1[32]; read_vec(bmsq[c], k, v1);
        float v2[32]; matvec32(slot[hwl + 4], v1, v2);
        float rmc[32]; matvec32(bmsq[c], v2, rmc);
        stage_vec(slot[hwl], k, rmc);
    }
    __syncthreads();
    if (hwl < 4) {
        float a[32]; read_vec(slot[hwl], k, a);
        jacobi32<NSWEEP_STAT>(a, k);
        float al = 0.f;
#pragma unroll
        for (int i = 0; i < 32; ++i) al = fmaf(a[i], a[i], al);
        al = fmaxf(al, 1e-30f);
        float wc = fmaxf(sqrtf(al), EPSC);
        coef[hwl][k] = (1.f / sqrtf(wc)) / al;
        stage_vec(slot[hwl], k, a);
    }
    __syncthreads();
    if (hwl < 4) {
        float o[32];
        recon32<false, true>(slot[hwl], coef[hwl], k, o);
        float* dst = rmisq_g + hwl * 1024 + k * 32;
#pragma unroll
        for (int i = 0; i < 32; ++i) dst[i] = o[i];
    }
}

// pass B blocked-2 packed: group-private slots throughout (no cross-group LDS).
__global__ __launch_bounds__(256) void k_passB_b2(const float* __restrict__ X, const float* __restrict__ rmisq_g,
                                                  const float* __restrict__ msq_g, const float* __restrict__ svec_g,
                                                  float* __restrict__ out) {
    __shared__ __align__(16) float slot[16][1028];
    __shared__ __align__(16) float rmi[1024];
    __shared__ __align__(16) float msl[1024];
    const int tid = threadIdx.x;
    const int g = tid >> 4, r = tid & 15;
    const int c0 = 2 * r, c1 = 2 * r + 1;
    const int bi = blockIdx.x;
    const int ch = bi & 3;
    const int gidx = (((bi >> 2) * 16) + g) * 4 + ch;
    const float sv = svec_g[ch];

    {   // stage rmi + msl swizzled
        const float4* s1 = (const float4*)(rmisq_g + ch * 1024);
        const float4* s2 = (const float4*)(msq_g + ch * 1024);
        int i4 = tid;
        *(float4*)(rmi + swz(4 * i4, i4 >> 3)) = s1[i4];
        *(float4*)(msl + swz(4 * i4, i4 >> 3)) = s2[i4];
    }
    {   // stage X swizzled
        const float4* xg = (const float4*)(X + (size_t)gidx * 1024);
        float* sg = slot[g];
#pragma unroll
        for (int q = 0; q < 16; ++q) {
            int i4 = q * 16 + r;
            *(float4*)(sg + swz(4 * i4, i4 >> 3)) = xg[i4];
        }
    }
    float b0f[32], b1f[32];
    {
        const float4* bs = (const float4*)(rmisq_g + ch * 1024);
#pragma unroll
        for (int t = 0; t < 8; ++t) {
            float4 v0 = bs[c0 * 8 + t];
            b0f[4*t+0]=v0.x; b0f[4*t+1]=v0.y; b0f[4*t+2]=v0.z; b0f[4*t+3]=v0.w;
            float4 v1 = bs[c1 * 8 + t];
            b1f[4*t+0]=v1.x; b1f[4*t+1]=v1.y; b1f[4*t+2]=v1.z; b1f[4*t+3]=v1.w;
        }
    }
    __syncthreads();
    v2f y0[16], y1[16];
    mv2(slot[g], b0f, b1f, y0, y1);                    // X * rmi-cols
    v2f a0[16], a1[16];
    {
        float w0a[32], w1a[32];
#pragma unroll
        for (int u = 0; u < 16; ++u) {
            w0a[2*u] = y0[u].x; w0a[2*u+1] = y0[u].y;
            w1a[2*u] = y1[u].x; w1a[2*u+1] = y1[u].y;
        }
        mv2(rmi, w0a, w1a, a0, a1);                    // inner cols c0,c1
    }
    float al0, al1;
    jacobi_b2p<NSWEEP_B>(a0, a1, al0, al1, r);
    al0 = fmaxf(al0, 1e-30f); al1 = fmaxf(al1, 1e-30f);
    float wc0 = fmaxf(sqrtf(al0), EPSC);
    float wc1 = fmaxf(sqrtf(al1), EPSC);
    float scl0 = sqrtf(expf(sv * logf(wc0)) / al0);    // sqrt(lam^s)/lam
    float scl1 = sqrtf(expf(sv * logf(wc1)) / al1);
    v2f cc0[16], cc1[16];
    {
        float w0a[32], w1a[32];
#pragma unroll
        for (int u = 0; u < 16; ++u) {
            w0a[2*u] = a0[u].x * scl0; w0a[2*u+1] = a0[u].y * scl0;
            w1a[2*u] = a1[u].x * scl1; w1a[2*u+1] = a1[u].y * scl1;
        }
        mv2(msl, w0a, w1a, cc0, cc1);                  // C cols = mean_sq * bh
    }
    {   // stage C (overwrite X; group-private, same-wave order)
        float* sg = slot[g];
#pragma unroll
        for (int t = 0; t < 8; ++t) {
            *(float4*)(sg + swz(c0 * 32 + 4 * t, c0)) = pk4(cc0[2*t], cc0[2*t+1]);
            *(float4*)(sg + swz(c1 * 32 + 4 * t, c1)) = pk4(cc1[2*t], cc1[2*t+1]);
        }
    }
    v2f x0[16], x1[16];
    mv2w<false>(slot[g], (const float*)nullptr, c0, c1, x0, x1);   // Xn = C C^T
    float* dst = out + (size_t)gidx * 1024;
#pragma unroll
    for (int u = 0; u < 16; ++u) {
        *(float2*)(dst + (2*u) * 32 + c0)     = make_float2(x0[u].x, x1[u].x);
        *(float2*)(dst + (2*u + 1) * 32 + c0) = make_float2(x0[u].y, x1[u].y);
    }
}

extern "C" void kernel_launch(void* const* d_in, const int* in_sizes, int n_in,
                              void* d_out, int out_size, void* d_ws, size_t ws_size,
                              hipStream_t stream) {
    const float* X     = (const float*)d_in[0];
    // d_in[1] running_mean, d_in[2] running_var: drop out exactly for ETA=1
    const float* meang = (const float*)d_in[3];
    const float* stdg  = (const float*)d_in[4];
    float* out = (float*)d_out;
    float* ws  = (float*)d_ws;
    (void)in_sizes; (void)n_in; (void)out_size;

    auto need = [](size_t ne) -> size_t {
        return (size_t)(32768ull + ne * 1024ull + ne * 32ull + 65536ull + 64ull) * 4ull;
    };
    int NE = (ws_size >= need(1024)) ? 1024 : 512;
    float* gtblk  = ws + OFF_DYN;
    float* sllblk = gtblk + (size_t)NE * 1024;
    float* gt2    = sllblk + (size_t)NE * 32;
    float* sll2   = gt2 + 65536;

    k_mean1<<<256, 256, 0, stream>>>(X, ws + OFF_PART1);
    k_mean2<<<64, 256, 0, stream>>>(ws + OFF_PART1, ws + OFF_BM);
    k_prep <<<1, 256, 0, stream>>>(ws + OFF_BM, meang, ws + OFF_BMSQ, ws + OFF_BMISQ, ws + OFF_MEANSQ);
    if (NE == 1024) {
        k_passA_b2<<<1024, 256, 0, stream>>>(X, ws + OFF_BMISQ, gtblk, sllblk);
    } else {
        k_passAL<<<512, 256, 0, stream>>>(X, ws + OFF_BMISQ, gtblk, sllblk, 4, 1024);
    }
    k_red  <<<64, 256, 0, stream>>>(gtblk, sllblk, gt2, sll2, NE / 64);
    k_stats<<<1, 256, 0, stream>>>(gt2, sll2, stdg, ws + OFF_BMSQ, ws + OFF_RMISQ, ws + OFF_SVEC);
    k_passB_b2<<<1024, 256, 0, stream>>>(X, ws + OFF_RMISQ, ws + OFF_MEANSQ, ws + OFF_SVEC, out);
}